// Round 7
// baseline (323.268 us; speedup 1.0000x reference)
//
#include <hip/hip_runtime.h>
#include <hip/hip_cooperative_groups.h>
#include <math.h>

namespace cg = cooperative_groups;

#define SLEN 2000
#define BATCH 8
#define MTOK 16000
#define WIN 99
#define XPAD 264

typedef __attribute__((ext_vector_type(8))) short short8;
typedef __attribute__((ext_vector_type(4))) float floatx4;

// ---------- bf16 helpers (bit-level, RNE) ----------
__device__ __forceinline__ float bf2f(unsigned int h) {
  union { unsigned int u; float f; } w; w.u = h << 16; return w.f;
}
__device__ __forceinline__ unsigned short f2bf(float f) {
  union { float f; unsigned int u; } w; w.f = f;
  return (unsigned short)((w.u + 0x7fffu + ((w.u >> 16) & 1u)) >> 16);
}

// async global->LDS, 16B per lane; lds base must be wave-uniform
typedef const __attribute__((address_space(1))) unsigned int* gas_t;
typedef __attribute__((address_space(3))) unsigned int* las_t;
__device__ __forceinline__ void gload_lds16(const unsigned short* g, unsigned short* l) {
  __builtin_amdgcn_global_load_lds((gas_t)g, (las_t)l, 16, 0, 0);
}

// ================= prep: 5 weight cvts + posenc + headprep (separate launch) =================
__device__ __forceinline__ void cvt4(const float* __restrict__ in,
                                     unsigned short* __restrict__ out, int i) {
  float4 v = ((const float4*)in)[i];
  ushort4 o;
  o.x = f2bf(v.x); o.y = f2bf(v.y); o.z = f2bf(v.z); o.w = f2bf(v.w);
  ((ushort4*)out)[i] = o;
}

__global__ __launch_bounds__(256) void k_prep(
    const float* __restrict__ wenc,     unsigned short* __restrict__ wencb,
    const float* __restrict__ wqk,      unsigned short* __restrict__ wqkb,
    const float* __restrict__ wout,     unsigned short* __restrict__ woutb,
    const float* __restrict__ wl1,      unsigned short* __restrict__ wl1b,
    const float* __restrict__ wl2,      unsigned short* __restrict__ wl2b,
    float* __restrict__ pe,
    const float* __restrict__ fc1w, const float* __restrict__ fc1b,
    const float* __restrict__ fc2w, const float* __restrict__ fc2b,
    const float* __restrict__ ln2w, const float* __restrict__ ln2b,
    float* __restrict__ hp) {
  __shared__ float red0[4], red1[4];
  const int bx = blockIdx.x, tid = threadIdx.x;
  if (bx < 64)         { cvt4(wenc, wencb, bx * 256 + tid); }
  else if (bx < 256)   { cvt4(wqk,  wqkb,  (bx - 64) * 256 + tid); }
  else if (bx < 320)   { cvt4(wout, woutb, (bx - 256) * 256 + tid); }
  else if (bx < 384)   { cvt4(wl1,  wl1b,  (bx - 320) * 256 + tid); }
  else if (bx < 448)   { cvt4(wl2,  wl2b,  (bx - 384) * 256 + tid); }
  else if (bx < 2448) {                                                   // posenc
    int idx = (bx - 448) * 256 + tid;
    int s = idx >> 8, d = idx & 255, p2 = d >> 1;
    float dv  = expf((float)p2 * -0.07195578415606394f);
    float ang = (float)s * dv;
    pe[idx] = (d & 1) ? cosf(ang) : sinf(ang);
  } else {                                                                // headprep
    int k = tid;
    float we = 0.f;
#pragma unroll 8
    for (int o = 0; o < 64; ++o) we += fc2w[o] * fc1w[o * 256 + k];
    float c1 = ln2w[k] * we;
    hp[k] = c1;
    float p0 = ln2b[k] * we;
    if (k < 64) p0 += fc2w[k] * fc1b[k];
    float s0 = p0, s1 = c1;
#pragma unroll
    for (int off = 32; off; off >>= 1) {
      s0 += __shfl_xor(s0, off);
      s1 += __shfl_xor(s1, off);
    }
    int wv = k >> 6;
    if ((k & 63) == 0) { red0[wv] = s0; red1[wv] = s1; }
    __syncthreads();
    if (k == 0) {
      hp[256] = red0[0] + red0[1] + red0[2] + red0[3] + fc2b[0];
      hp[257] = red1[0] + red1[1] + red1[2] + red1[3];
    }
  }
}

// ================= mega kernel: pre | attn | post with grid sync =================
// 512 blocks x 256 thr, __launch_bounds__(256,2) + 64.7KB LDS -> 2 blocks/CU
// co-resident (160KB LDS, VGPR<=256). phase=-1: cooperative, all 3 phases with
// grid.sync(); phase=0/1/2: single phase (fallback path, plain launches).
struct MegaArgs {
  const float* src;
  const unsigned short* wenc; const float* benc;
  const float* pe;
  const unsigned short* wqk; const float* bqk;
  unsigned short* xb; unsigned short* qkvb;
  unsigned short* ctxb;
  const unsigned short* wout; const float* bout;
  const float* ln1w; const float* ln1b;
  const unsigned short* w1; const float* b1;
  const unsigned short* w2; const float* b2;
  const float* hp; float* out;
};

#define KPAD 136
#define VPAD 184
#define PPAD 132
#define UNION 176
#define SMEM_BYTES 64768   // max(pre 53760, attn 64768, post 57600)

__global__ __launch_bounds__(256, 2) void k_mega(MegaArgs a, int phase) {
  __shared__ __align__(16) unsigned char smem[SMEM_BYTES];
  const int tid  = threadIdx.x;
  const int lane = tid & 63;
  const int w    = tid >> 6;
  const int bx   = blockIdx.x;
  const int kq = lane >> 4, ml = lane & 15;

  // =============== phase 0: encoder + qkv (32-token units, 500 active) ===============
  if ((phase < 0 || phase == 0) && bx < 500) {
    const int m0 = bx * 32;
    unsigned short* Xt   = (unsigned short*)smem;               // 32*264 shorts
    unsigned short* Achk = (unsigned short*)(smem + 16896);     // 2 x 1024 shorts
    unsigned short* Bchk = (unsigned short*)(smem + 20992);     // 2 x 8192 shorts
    const int wrow = (w & 1) * 16;
    const int c0   = (w >> 1) * 128;
    const int myrow = wrow + ml;
    const int sa = kq ^ ((myrow >> 1) & 3);

    // A-cvt staging map: 32 rows x 32k chunk = 256 x 8B
    const int ar = tid >> 3, sub = tid & 7;
    const int as16 = sub >> 1, ahalf = sub & 1;
    const int ac = as16 ^ ((ar >> 1) & 3);
    const float* asrc = a.src + (size_t)(m0 + ar) * 256 + ac * 8 + ahalf * 4;
    const int aoff = ar * 32 + as16 * 8 + ahalf * 4;

    int brow[4], bsc[4];
#pragma unroll
    for (int i = 0; i < 4; ++i) {
      brow[i] = (w * 4 + i) * 16 + (lane >> 2);
      bsc[i]  = (lane & 3) ^ ((brow[i] >> 1) & 3);
    }

    // ---- stage 1: x = src @ Wenc^T (double-buffered) ----
    floatx4 acc[8] = {};
    {
      float4 v = *(const float4*)asrc;
      unsigned short t4[4] = {f2bf(v.x), f2bf(v.y), f2bf(v.z), f2bf(v.w)};
      *(uint2*)&Achk[aoff] = *(const uint2*)t4;
#pragma unroll
      for (int i = 0; i < 4; ++i)
        gload_lds16(a.wenc + (size_t)brow[i] * 256 + bsc[i] * 8, &Bchk[(w * 4 + i) * 512]);
    }
    for (int k8 = 0; k8 < 8; ++k8) {
      __syncthreads();
      if (k8 < 7) {
        int nb = (k8 & 1) ^ 1, kt = (k8 + 1) * 32;
        float4 v = *(const float4*)(asrc + kt);
        unsigned short t4[4] = {f2bf(v.x), f2bf(v.y), f2bf(v.z), f2bf(v.w)};
        *(uint2*)&Achk[nb * 1024 + aoff] = *(const uint2*)t4;
#pragma unroll
        for (int i = 0; i < 4; ++i)
          gload_lds16(a.wenc + (size_t)brow[i] * 256 + kt + bsc[i] * 8,
                      &Bchk[nb * 8192 + (w * 4 + i) * 512]);
      }
      int buf = k8 & 1;
      short8 af = *(const short8*)&Achk[buf * 1024 + myrow * 32 + sa * 8];
#pragma unroll
      for (int nt = 0; nt < 8; ++nt) {
        int n = c0 + nt * 16 + ml;
        int sb = kq ^ ((n >> 1) & 3);
        short8 bf = *(const short8*)&Bchk[buf * 8192 + n * 32 + sb * 8];
        acc[nt] = __builtin_amdgcn_mfma_f32_16x16x32_bf16(af, bf, acc[nt], 0, 0, 0);
      }
    }
    // epilogue: + bias + posenc -> Xt (LDS) + xb (global)
#pragma unroll
    for (int nt = 0; nt < 8; ++nt)
#pragma unroll
      for (int r = 0; r < 4; ++r) {
        int lr  = wrow + kq * 4 + r;
        int row = m0 + lr;
        int col = c0 + nt * 16 + ml;
        float v = acc[nt][r] + a.benc[col] + a.pe[(size_t)(row % SLEN) * 256 + col];
        unsigned short hv = f2bf(v);
        Xt[lr * XPAD + col] = hv;
        a.xb[(size_t)row * 256 + col] = hv;
      }
    __syncthreads();

    // ---- stage 2: qkv = Xt @ Wqk^T, 3 passes ----
    for (int p = 0; p < 3; ++p) {
      const unsigned short* Wp = a.wqk + (size_t)p * 65536;
      floatx4 a2[8] = {};
#pragma unroll
      for (int i = 0; i < 4; ++i)
        gload_lds16(Wp + (size_t)brow[i] * 256 + bsc[i] * 8, &Bchk[(w * 4 + i) * 512]);
      for (int k8 = 0; k8 < 8; ++k8) {
        __syncthreads();
        if (k8 < 7) {
          int nb = (k8 & 1) ^ 1, kt = (k8 + 1) * 32;
#pragma unroll
          for (int i = 0; i < 4; ++i)
            gload_lds16(Wp + (size_t)brow[i] * 256 + kt + bsc[i] * 8,
                        &Bchk[nb * 8192 + (w * 4 + i) * 512]);
        }
        int buf = k8 & 1;
        short8 af = *(const short8*)&Xt[myrow * XPAD + k8 * 32 + kq * 8];
#pragma unroll
        for (int nt = 0; nt < 8; ++nt) {
          int n = c0 + nt * 16 + ml;
          int sb = kq ^ ((n >> 1) & 3);
          short8 bf = *(const short8*)&Bchk[buf * 8192 + n * 32 + sb * 8];
          a2[nt] = __builtin_amdgcn_mfma_f32_16x16x32_bf16(af, bf, a2[nt], 0, 0, 0);
        }
      }
#pragma unroll
      for (int nt = 0; nt < 8; ++nt)
#pragma unroll
        for (int r = 0; r < 4; ++r) {
          int row = m0 + wrow + kq * 4 + r;
          int cg2 = p * 256 + c0 + nt * 16 + ml;
          a.qkvb[(size_t)row * 768 + cg2] = f2bf(a2[nt][r] + a.bqk[cg2]);
        }
      if (p < 2) __syncthreads();
    }
  }
  if (phase < 0) cg::this_grid().sync();

  // =============== phase 1: banded MFMA attention (512 units, verified body) ===============
  if (phase < 0 || phase == 1) {
    const int u  = bx;
    const int i0 = (u & 31) * 64;
    const int b  = (u >> 5) & 7;
    const int h  = (u >> 8) & 1;
    unsigned short* KV = (unsigned short*)smem;                 // 176*136 shorts
    unsigned short* Ps = (unsigned short*)(smem + 47872);       // 4*16*132 shorts
    const int jmin_u = i0 - WIN;
    const float scale = 0.08838834764831845f;

    const int qrow = i0 + w * 16 + (lane & 15);
    const unsigned short* qptr =
        a.qkvb + (size_t)(b * SLEN + min(qrow, SLEN - 1)) * 768 + h * 128 + (lane >> 4) * 8;
    short8 qf[4];
#pragma unroll
    for (int kc = 0; kc < 4; ++kc) qf[kc] = *(const short8*)(qptr + kc * 32);

    for (int it = 0; it < 11; ++it) {
      int idx = it * 256 + tid;
      int row = idx >> 4;
      int c8  = idx & 15;
      int j = jmin_u + row;
      uint4 v = make_uint4(0u, 0u, 0u, 0u);
      if (j >= 0 && j < SLEN)
        v = *(const uint4*)(a.qkvb + (size_t)(b * SLEN + j) * 768 + 256 + h * 128 + c8 * 8);
      *(uint4*)&KV[row * KPAD + c8 * 8] = v;
    }
    __syncthreads();

    const int koff = w * 16;
    floatx4 sc[8] = {};
#pragma unroll
    for (int kt = 0; kt < 8; ++kt) {
#pragma unroll
      for (int kc = 0; kc < 4; ++kc) {
        short8 kf = *(const short8*)&KV[(koff + kt * 16 + (lane & 15)) * KPAD
                                        + kc * 32 + (lane >> 4) * 8];
        sc[kt] = __builtin_amdgcn_mfma_f32_16x16x32_bf16(qf[kc], kf, sc[kt], 0, 0, 0);
      }
    }

    const int qme = i0 + w * 16 + (lane >> 4) * 4;
    const int jme = jmin_u + koff + (lane & 15);
    float mx[4] = {-1e30f, -1e30f, -1e30f, -1e30f};
#pragma unroll
    for (int kt = 0; kt < 8; ++kt) {
#pragma unroll
      for (int r = 0; r < 4; ++r) {
        int j = jme + kt * 16, q = qme + r;
        bool ok = (j >= 0) && (j >= q - WIN) && (j <= q);
        float s = ok ? sc[kt][r] : -1e30f;
        sc[kt][r] = s;
        mx[r] = fmaxf(mx[r], s);
      }
    }
#pragma unroll
    for (int r = 0; r < 4; ++r)
#pragma unroll
      for (int off = 8; off; off >>= 1) mx[r] = fmaxf(mx[r], __shfl_xor(mx[r], off, 16));

    float sum[4] = {0.f, 0.f, 0.f, 0.f};
#pragma unroll
    for (int kt = 0; kt < 8; ++kt)
#pragma unroll
      for (int r = 0; r < 4; ++r) {
        float e = __expf((sc[kt][r] - mx[r]) * scale);
        sc[kt][r] = e;
        sum[r] += e;
      }
#pragma unroll
    for (int r = 0; r < 4; ++r)
#pragma unroll
      for (int off = 8; off; off >>= 1) sum[r] += __shfl_xor(sum[r], off, 16);
    float rinv[4];
#pragma unroll
    for (int r = 0; r < 4; ++r) rinv[r] = 1.f / sum[r];

    unsigned short* pw = Ps + w * (16 * PPAD);
#pragma unroll
    for (int kt = 0; kt < 8; ++kt)
#pragma unroll
      for (int r = 0; r < 4; ++r)
        pw[((lane >> 4) * 4 + r) * PPAD + kt * 16 + (lane & 15)] = f2bf(sc[kt][r]);
    __syncthreads();

    for (int it = 0; it < 12; ++it) {
      int idx = it * 256 + tid;
      int grp = idx >> 6;
      int key = (grp >> 4) * 64 + (idx & 63);
      int c8  = grp & 15;
      if (key < UNION) {
        int j = jmin_u + key;
        uint4 v = make_uint4(0u, 0u, 0u, 0u);
        if (j >= 0 && j < SLEN)
          v = *(const uint4*)(a.qkvb + (size_t)(b * SLEN + j) * 768 + 512 + h * 128 + c8 * 8);
        unsigned short e[8];
        *(uint4*)e = v;
        int d0 = c8 * 8;
#pragma unroll
        for (int i = 0; i < 8; ++i) KV[(d0 + i) * VPAD + key] = e[i];
      }
    }
    __syncthreads();

    floatx4 ov[8] = {};
#pragma unroll
    for (int kc = 0; kc < 4; ++kc) {
      short8 pf = *(const short8*)&pw[(lane & 15) * PPAD + kc * 32 + (lane >> 4) * 8];
#pragma unroll
      for (int dt = 0; dt < 8; ++dt) {
        short8 vf = *(const short8*)&KV[(dt * 16 + (lane & 15)) * VPAD
                                        + koff + kc * 32 + (lane >> 4) * 8];
        ov[dt] = __builtin_amdgcn_mfma_f32_16x16x32_bf16(pf, vf, ov[dt], 0, 0, 0);
      }
    }

#pragma unroll
    for (int dt = 0; dt < 8; ++dt)
#pragma unroll
      for (int r = 0; r < 4; ++r) {
        int q = qme + r;
        if (q < SLEN)
          a.ctxb[(size_t)(b * SLEN + q) * 256 + h * 128 + dt * 16 + (lane & 15)] =
              f2bf(ov[dt][r] * rinv[r]);
      }
  }
  if (phase < 0) cg::this_grid().sync();

  // =============== phase 2: out_proj+LN1+FFN+LN2+head (32-token units, 500 active) ===============
  if ((phase < 0 || phase == 2) && bx < 500) {
    const int m0 = bx * 32;
    unsigned short* X1   = (unsigned short*)smem;               // 32*264 shorts
    unsigned short* Achk = (unsigned short*)(smem + 16896);     // 2 x 1024 shorts
    unsigned short* Bchk = (unsigned short*)(smem + 20992);     // 2 x 8192 shorts
    float* lnred = (float*)(smem + 53760);                      // [2][32][3]
    float* lnp   = (float*)(smem + 54528);                      // 512 floats
    float* c1s   = (float*)(smem + 56576);                      // 256 floats
    const int wrow = (w & 1) * 16;
    const int c0   = (w >> 1) * 128;
    const int half = w >> 1;
    const int myrow = wrow + ml;
    const int sa = kq ^ ((myrow >> 1) & 3);

    lnp[tid] = a.ln1w[tid];
    lnp[256 + tid] = a.ln1b[tid];
    c1s[tid] = a.hp[tid];
    const float c0h = a.hp[256], sc1 = a.hp[257];

    int brow[4], bsc[4];
#pragma unroll
    for (int i = 0; i < 4; ++i) {
      brow[i] = (w * 4 + i) * 16 + (lane >> 2);
      bsc[i]  = (lane & 3) ^ ((brow[i] >> 1) & 3);
    }
    const int arow = (w & 1) * 16 + (lane >> 2);   // used when w<2
    const int aasc = (lane & 3) ^ ((arow >> 1) & 3);
    const unsigned short* actx = a.ctxb + (size_t)(m0 + arow) * 256 + aasc * 8;

    // ---- stage A: ctx @ Wout^T + bout + x -> LN1 ----
    floatx4 acc[8] = {};
    {
      if (w < 2) gload_lds16(actx, &Achk[w * 512]);
#pragma unroll
      for (int i = 0; i < 4; ++i)
        gload_lds16(a.wout + (size_t)brow[i] * 256 + bsc[i] * 8, &Bchk[(w * 4 + i) * 512]);
    }
    for (int k8 = 0; k8 < 8; ++k8) {
      __syncthreads();
      if (k8 < 7) {
        int nb = (k8 & 1) ^ 1, kt = (k8 + 1) * 32;
        if (w < 2) gload_lds16(actx + kt, &Achk[nb * 1024 + w * 512]);
#pragma unroll
        for (int i = 0; i < 4; ++i)
          gload_lds16(a.wout + (size_t)brow[i] * 256 + kt + bsc[i] * 8,
                      &Bchk[nb * 8192 + (w * 4 + i) * 512]);
      }
      int buf = k8 & 1;
      short8 af = *(const short8*)&Achk[buf * 1024 + myrow * 32 + sa * 8];
#pragma unroll
      for (int nt = 0; nt < 8; ++nt) {
        int n = c0 + nt * 16 + ml;
        int sb = kq ^ ((n >> 1) & 3);
        short8 bf = *(const short8*)&Bchk[buf * 8192 + n * 32 + sb * 8];
        acc[nt] = __builtin_amdgcn_mfma_f32_16x16x32_bf16(af, bf, acc[nt], 0, 0, 0);
      }
    }
    float s_[4] = {0.f, 0.f, 0.f, 0.f}, q_[4] = {0.f, 0.f, 0.f, 0.f};
#pragma unroll
    for (int nt = 0; nt < 8; ++nt)
#pragma unroll
      for (int r = 0; r < 4; ++r) {
        int row = m0 + wrow + kq * 4 + r;
        int col = c0 + nt * 16 + ml;
        float v = acc[nt][r] + a.bout[col] + bf2f(a.xb[(size_t)row * 256 + col]);
        acc[nt][r] = v;
        s_[r] += v;
        q_[r] += v * v;
      }
#pragma unroll
    for (int r = 0; r < 4; ++r)
#pragma unroll
      for (int off = 8; off; off >>= 1) {
        s_[r] += __shfl_xor(s_[r], off, 16);
        q_[r] += __shfl_xor(q_[r], off, 16);
      }
    if (ml == 0) {
#pragma unroll
      for (int r = 0; r < 4; ++r) {
        int lr = wrow + kq * 4 + r;
        lnred[half * 96 + lr * 3 + 0] = s_[r];
        lnred[half * 96 + lr * 3 + 1] = q_[r];
      }
    }
    __syncthreads();
    floatx4 x1sav[8];
#pragma unroll
    for (int r = 0; r < 4; ++r) {
      int lr = wrow + kq * 4 + r;
      float s = lnred[lr * 3 + 0] + lnred[96 + lr * 3 + 0];
      float q = lnred[lr * 3 + 1] + lnred[96 + lr * 3 + 1];
      float mu  = s * (1.f / 256.f);
      float var = q * (1.f / 256.f) - mu * mu;
      float rr  = rsqrtf(var + 1e-5f);
#pragma unroll
      for (int nt = 0; nt < 8; ++nt) {
        int col = c0 + nt * 16 + ml;
        float x1 = (acc[nt][r] - mu) * rr * lnp[col] + lnp[256 + col];
        x1sav[nt][r] = x1;
        X1[lr * XPAD + col] = f2bf(x1);
      }
    }
    __syncthreads();

    // ---- stage B: h = relu(x1 @ W1^T + b1) ----
#pragma unroll
    for (int nt = 0; nt < 8; ++nt) acc[nt] = (floatx4){0.f, 0.f, 0.f, 0.f};
#pragma unroll
    for (int i = 0; i < 4; ++i)
      gload_lds16(a.w1 + (size_t)brow[i] * 256 + bsc[i] * 8, &Bchk[(w * 4 + i) * 512]);
    for (int k8 = 0; k8 < 8; ++k8) {
      __syncthreads();
      if (k8 < 7) {
        int nb = (k8 & 1) ^ 1, kt = (k8 + 1) * 32;
#pragma unroll
        for (int i = 0; i < 4; ++i)
          gload_lds16(a.w1 + (size_t)brow[i] * 256 + kt + bsc[i] * 8,
                      &Bchk[nb * 8192 + (w * 4 + i) * 512]);
      }
      int buf = k8 & 1;
      short8 af = *(const short8*)&X1[myrow * XPAD + k8 * 32 + kq * 8];
#pragma unroll
      for (int nt = 0; nt < 8; ++nt) {
        int n = c0 + nt * 16 + ml;
        int sb = kq ^ ((n >> 1) & 3);
        short8 bf = *(const short8*)&Bchk[buf * 8192 + n * 32 + sb * 8];
        acc[nt] = __builtin_amdgcn_mfma_f32_16x16x32_bf16(af, bf, acc[nt], 0, 0, 0);
      }
    }
    __syncthreads();   // all waves done reading x1 from X1
#pragma unroll
    for (int nt = 0; nt < 8; ++nt)
#pragma unroll
      for (int r = 0; r < 4; ++r) {
        int lr  = wrow + kq * 4 + r;
        int col = c0 + nt * 16 + ml;
        X1[lr * XPAD + col] = f2bf(fmaxf(acc[nt][r] + a.b1[col], 0.f));
      }

    // ---- stage C: o = h @ W2^T + b2 + x1 -> LN2 + collapsed head ----
#pragma unroll
    for (int nt = 0; nt < 8; ++nt) acc[nt] = (floatx4){0.f, 0.f, 0.f, 0.f};
#pragma unroll
    for (int i = 0; i < 4; ++i)
      gload_lds16(a.w2 + (size_t)brow[i] * 256 + bsc[i] * 8, &Bchk[(w * 4 + i) * 512]);
    for (int k8 = 0; k8 < 8; ++k8) {
      __syncthreads();   // also orders the h writes above before first compute
      if (k8 < 7) {
        int nb = (k8 & 1) ^ 1, kt = (k8 + 1) * 32;
#pragma unroll
        for (int i = 0; i < 4; ++i)
          gload_lds16(a.w2 + (size_t)brow[i] * 256 + kt + bsc[i] * 8,
                      &Bchk[nb * 8192 + (w * 4 + i) * 512]);
      }
      int buf = k8 & 1;
      short8 af = *(const short8*)&X1[myrow * XPAD + k8 * 32 + kq * 8];
#pragma unroll
      for (int nt = 0; nt < 8; ++nt) {
        int n = c0 + nt * 16 + ml;
        int sb = kq ^ ((n >> 1) & 3);
        short8 bf = *(const short8*)&Bchk[buf * 8192 + n * 32 + sb * 8];
        acc[nt] = __builtin_amdgcn_mfma_f32_16x16x32_bf16(af, bf, acc[nt], 0, 0, 0);
      }
    }
    float ss[4] = {0.f, 0.f, 0.f, 0.f}, qq[4] = {0.f, 0.f, 0.f, 0.f}, dd[4] = {0.f, 0.f, 0.f, 0.f};
#pragma unroll
    for (int nt = 0; nt < 8; ++nt)
#pragma unroll
      for (int r = 0; r < 4; ++r) {
        int col = c0 + nt * 16 + ml;
        float v = acc[nt][r] + a.b2[col] + x1sav[nt][r];
        ss[r] += v;
        qq[r] += v * v;
        dd[r] += v * c1s[col];
      }
#pragma unroll
    for (int r = 0; r < 4; ++r)
#pragma unroll
      for (int off = 8; off; off >>= 1) {
        ss[r] += __shfl_xor(ss[r], off, 16);
        qq[r] += __shfl_xor(qq[r], off, 16);
        dd[r] += __shfl_xor(dd[r], off, 16);
      }
    if (ml == 0) {
#pragma unroll
      for (int r = 0; r < 4; ++r) {
        int lr = wrow + kq * 4 + r;
        lnred[half * 96 + lr * 3 + 0] = ss[r];
        lnred[half * 96 + lr * 3 + 1] = qq[r];
        lnred[half * 96 + lr * 3 + 2] = dd[r];
      }
    }
    __syncthreads();
    if (w < 2 && ml == 0) {
#pragma unroll
      for (int r = 0; r < 4; ++r) {
        int lr = wrow + kq * 4 + r;
        float s = lnred[lr * 3 + 0] + lnred[96 + lr * 3 + 0];
        float q = lnred[lr * 3 + 1] + lnred[96 + lr * 3 + 1];
        float d = lnred[lr * 3 + 2] + lnred[96 + lr * 3 + 2];
        float mu  = s * (1.f / 256.f);
        float var = q * (1.f / 256.f) - mu * mu;
        float rr  = rsqrtf(var + 1e-5f);
        a.out[m0 + lr] = rr * (d - mu * sc1) + c0h;
      }
    }
  }
}

extern "C" void kernel_launch(void* const* d_in, const int* in_sizes, int n_in,
                              void* d_out, int out_size, void* d_ws, size_t ws_size,
                              hipStream_t stream) {
  const float* src        = (const float*)d_in[0];
  // d_in[1] = input_lengths (unused)
  const float* W_enc      = (const float*)d_in[2];
  const float* b_enc      = (const float*)d_in[3];
  const float* in_proj_w  = (const float*)d_in[4];
  const float* in_proj_b  = (const float*)d_in[5];
  const float* out_proj_w = (const float*)d_in[6];
  const float* out_proj_b = (const float*)d_in[7];
  const float* ln1_w      = (const float*)d_in[8];
  const float* ln1_b      = (const float*)d_in[9];
  const float* lin1_w     = (const float*)d_in[10];
  const float* lin1_b     = (const float*)d_in[11];
  const float* lin2_w     = (const float*)d_in[12];
  const float* lin2_b     = (const float*)d_in[13];
  const float* ln2_w      = (const float*)d_in[14];
  const float* ln2_b      = (const float*)d_in[15];
  const float* fc1_w      = (const float*)d_in[16];
  const float* fc1_b      = (const float*)d_in[17];
  const float* fc2_w      = (const float*)d_in[18];
  const float* fc2_b      = (const float*)d_in[19];

  char* p = (char*)d_ws;
  float* pe            = (float*)p;           p += (size_t)SLEN * 256 * 4;
  float* hp            = (float*)p;           p += 2048;   // 258 floats used
  unsigned short* xb   = (unsigned short*)p;  p += (size_t)MTOK * 256 * 2;
  unsigned short* qkvb = (unsigned short*)p;  p += (size_t)MTOK * 768 * 2;
  unsigned short* ctxb = (unsigned short*)p;  p += (size_t)MTOK * 256 * 2;
  unsigned short* wencb= (unsigned short*)p;  p += 256 * 256 * 2;
  unsigned short* wqkb = (unsigned short*)p;  p += 768 * 256 * 2;
  unsigned short* woutb= (unsigned short*)p;  p += 256 * 256 * 2;
  unsigned short* wl1b = (unsigned short*)p;  p += 256 * 256 * 2;
  unsigned short* wl2b = (unsigned short*)p;  p += 256 * 256 * 2;

  k_prep<<<2449, 256, 0, stream>>>(W_enc, wencb, in_proj_w, wqkb,
                                   out_proj_w, woutb, lin1_w, wl1b, lin2_w, wl2b,
                                   pe, fc1_w, fc1_b, fc2_w, fc2_b, ln2_w, ln2_b, hp);

  MegaArgs ma;
  ma.src = src;  ma.wenc = wencb; ma.benc = b_enc; ma.pe = pe;
  ma.wqk = wqkb; ma.bqk = in_proj_b;
  ma.xb = xb; ma.qkvb = qkvb; ma.ctxb = ctxb;
  ma.wout = woutb; ma.bout = out_proj_b;
  ma.ln1w = ln1_w; ma.ln1b = ln1_b;
  ma.w1 = wl1b; ma.b1 = lin1_b;
  ma.w2 = wl2b; ma.b2 = lin2_b;
  ma.hp = hp; ma.out = (float*)d_out;

  int ph = -1;
  void* kargs[] = { (void*)&ma, (void*)&ph };
  hipError_t e = hipLaunchCooperativeKernel((const void*)k_mega, dim3(512), dim3(256),
                                            kargs, 0, stream);
  if (e != hipSuccess) {
    // fallback: three plain launches (stream order provides the inter-phase sync)
    k_mega<<<512, 256, 0, stream>>>(ma, 0);
    k_mega<<<512, 256, 0, stream>>>(ma, 1);
    k_mega<<<512, 256, 0, stream>>>(ma, 2);
  }
}

// Round 8
// 181.862 us; speedup vs baseline: 1.7776x; 1.7776x over previous
//
#include <hip/hip_runtime.h>
#include <math.h>

#define SLEN 2000
#define BATCH 8
#define MTOK 16000
#define WIN 99

typedef __attribute__((ext_vector_type(8))) short short8;
typedef __attribute__((ext_vector_type(4))) float floatx4;

// ---------- bf16 helpers (bit-level, RNE) ----------
__device__ __forceinline__ float bf2f(unsigned int h) {
  union { unsigned int u; float f; } w; w.u = h << 16; return w.f;
}
__device__ __forceinline__ unsigned short f2bf(float f) {
  union { float f; unsigned int u; } w; w.f = f;
  return (unsigned short)((w.u + 0x7fffu + ((w.u >> 16) & 1u)) >> 16);
}

// async global->LDS, 16B per lane; lds base must be wave-uniform
typedef const __attribute__((address_space(1))) unsigned int* gas_t;
typedef __attribute__((address_space(3))) unsigned int* las_t;
__device__ __forceinline__ void gload_lds16(const unsigned short* g, unsigned short* l) {
  __builtin_amdgcn_global_load_lds((gas_t)g, (las_t)l, 16, 0, 0);
}

// ================= prep: 5 weight cvts + posenc + headprep =================
__device__ __forceinline__ void cvt4(const float* __restrict__ in,
                                     unsigned short* __restrict__ out, int i) {
  float4 v = ((const float4*)in)[i];
  ushort4 o;
  o.x = f2bf(v.x); o.y = f2bf(v.y); o.z = f2bf(v.z); o.w = f2bf(v.w);
  ((ushort4*)out)[i] = o;
}

__global__ __launch_bounds__(256) void k_prep(
    const float* __restrict__ wenc,     unsigned short* __restrict__ wencb,
    const float* __restrict__ wqk,      unsigned short* __restrict__ wqkb,
    const float* __restrict__ wout,     unsigned short* __restrict__ woutb,
    const float* __restrict__ wl1,      unsigned short* __restrict__ wl1b,
    const float* __restrict__ wl2,      unsigned short* __restrict__ wl2b,
    float* __restrict__ pe,
    const float* __restrict__ fc1w, const float* __restrict__ fc1b,
    const float* __restrict__ fc2w, const float* __restrict__ fc2b,
    const float* __restrict__ ln2w, const float* __restrict__ ln2b,
    float* __restrict__ hp) {
  __shared__ float red0[4], red1[4];
  const int bx = blockIdx.x, tid = threadIdx.x;
  if (bx < 64)         { cvt4(wenc, wencb, bx * 256 + tid); }
  else if (bx < 256)   { cvt4(wqk,  wqkb,  (bx - 64) * 256 + tid); }
  else if (bx < 320)   { cvt4(wout, woutb, (bx - 256) * 256 + tid); }
  else if (bx < 384)   { cvt4(wl1,  wl1b,  (bx - 320) * 256 + tid); }
  else if (bx < 448)   { cvt4(wl2,  wl2b,  (bx - 384) * 256 + tid); }
  else if (bx < 948) {                                       // posenc, float4/thread
    int i4 = (bx - 448) * 256 + tid;      // [0, 128000)
    int e0 = i4 * 4;
    int s  = e0 >> 8;
    int d0 = e0 & 255;                    // 4-aligned
    float dv0 = expf((float)(d0 >> 1) * -0.07195578415606394f);
    float dv1 = expf((float)((d0 >> 1) + 1) * -0.07195578415606394f);
    float a0 = (float)s * dv0, a1 = (float)s * dv1;
    float4 o = make_float4(sinf(a0), cosf(a0), sinf(a1), cosf(a1));
    ((float4*)pe)[i4] = o;
  } else {                                                   // headprep (1 block)
    int k = tid;
    float we = 0.f;
#pragma unroll 8
    for (int o = 0; o < 64; ++o) we += fc2w[o] * fc1w[o * 256 + k];
    float c1 = ln2w[k] * we;
    hp[k] = c1;
    float p0 = ln2b[k] * we;
    if (k < 64) p0 += fc2w[k] * fc1b[k];
    float s0 = p0, s1 = c1;
#pragma unroll
    for (int off = 32; off; off >>= 1) {
      s0 += __shfl_xor(s0, off);
      s1 += __shfl_xor(s1, off);
    }
    int wv = k >> 6;
    if ((k & 63) == 0) { red0[wv] = s0; red1[wv] = s1; }
    __syncthreads();
    if (k == 0) {
      hp[256] = red0[0] + red0[1] + red0[2] + red0[3] + fc2b[0];
      hp[257] = red1[0] + red1[1] + red1[2] + red1[3];
    }
  }
}

// ================= fused encoder + qkv projection =================
// grid (250, 2) x 64 tokens. Both y-blocks compute x = src@Wenc^T locally
// (cheap duplicate, bitwise-identical); y=0 then does the q pass and writes
// xb; y=1 does the k and v passes. 500 blocks -> 2 blocks/CU to hide the
// global_load_lds barrier drains (R6 had 250 -> 1/CU, latency-exposed).
#define XPAD 264

__global__ __launch_bounds__(256) void k_pre(
    const float* __restrict__ src,
    const unsigned short* __restrict__ wenc, const float* __restrict__ benc,
    const float* __restrict__ pe,
    const unsigned short* __restrict__ wqk, const float* __restrict__ bqk,
    unsigned short* __restrict__ xb, unsigned short* __restrict__ qkvb) {
  __shared__ __align__(16) unsigned short Xt[64 * XPAD];     // 33792 B
  __shared__ __align__(16) unsigned short Achk[64 * 32];     // 4096 B
  __shared__ __align__(16) unsigned short Bchk[256 * 32];    // 16384 B
  const int tid = threadIdx.x, lane = tid & 63, w = tid >> 6;
  const int m0 = blockIdx.x * 64;
  const int yy = blockIdx.y;
  const int plo = yy ? 1 : 0;
  const int phi = yy ? 3 : 1;
  const int kq = lane >> 4, ml = lane & 15;
  const int myrow = w * 16 + ml;                     // A-frag row (local)
  const int cq = lane >> 4, cl = lane & 15;          // C-layout

  // A-cvt staging: thread -> (row ar, stored slot as), fetch chunk ac
  const int ar = tid >> 2, as = tid & 3;
  const int ac = as ^ ((ar >> 1) & 3);
  const float* asrc = src + (size_t)(m0 + ar) * 256 + ac * 8;

  // B staging (global_load_lds): wave w, issue i: 16 rows each
  int brow[4], bsc[4];
#pragma unroll
  for (int i = 0; i < 4; ++i) {
    brow[i] = (w * 4 + i) * 16 + (lane >> 2);
    bsc[i]  = (lane & 3) ^ ((brow[i] >> 1) & 3);
  }

  // ---- stage 1: x = src @ Wenc^T ----
  floatx4 acc[16] = {};
  for (int kt = 0; kt < 256; kt += 32) {
    __syncthreads();
    {  // A: fp32 load + cvt + ds_write (swizzled slot)
      float4 v0 = *(const float4*)(asrc + kt);
      float4 v1 = *(const float4*)(asrc + kt + 4);
      unsigned short t8[8] = {f2bf(v0.x), f2bf(v0.y), f2bf(v0.z), f2bf(v0.w),
                              f2bf(v1.x), f2bf(v1.y), f2bf(v1.z), f2bf(v1.w)};
      *(uint4*)&Achk[ar * 32 + as * 8] = *(const uint4*)t8;
    }
#pragma unroll
    for (int i = 0; i < 4; ++i)
      gload_lds16(wenc + (size_t)brow[i] * 256 + kt + bsc[i] * 8, &Bchk[(w * 4 + i) * 512]);
    __syncthreads();

    int sa = kq ^ ((myrow >> 1) & 3);
    short8 af = *(const short8*)&Achk[myrow * 32 + sa * 8];
#pragma unroll
    for (int nt = 0; nt < 16; ++nt) {
      int n = nt * 16 + ml;
      int sb = kq ^ ((n >> 1) & 3);
      short8 bf = *(const short8*)&Bchk[n * 32 + sb * 8];
      acc[nt] = __builtin_amdgcn_mfma_f32_16x16x32_bf16(af, bf, acc[nt], 0, 0, 0);
    }
  }
  // epilogue: + bias + posenc -> Xt (LDS); xb (global) from y=0 only
#pragma unroll
  for (int nt = 0; nt < 16; ++nt) {
#pragma unroll
    for (int r = 0; r < 4; ++r) {
      int lrow = w * 16 + cq * 4 + r;
      int row  = m0 + lrow;
      int col  = nt * 16 + cl;
      float v = acc[nt][r] + benc[col] + pe[(size_t)(row % SLEN) * 256 + col];
      unsigned short hv = f2bf(v);
      Xt[lrow * XPAD + col] = hv;
      if (yy == 0) xb[(size_t)row * 256 + col] = hv;
    }
  }

  // ---- stage 2: qkv passes (y=0: q; y=1: k,v) ----
  for (int p = plo; p < phi; ++p) {
    floatx4 a2[16] = {};
    for (int kt = 0; kt < 256; kt += 32) {
      __syncthreads();
#pragma unroll
      for (int i = 0; i < 4; ++i)
        gload_lds16(wqk + (size_t)(p * 256 + brow[i]) * 256 + kt + bsc[i] * 8,
                    &Bchk[(w * 4 + i) * 512]);
      __syncthreads();
      short8 af = *(const short8*)&Xt[myrow * XPAD + kt + kq * 8];
#pragma unroll
      for (int nt = 0; nt < 16; ++nt) {
        int n = nt * 16 + ml;
        int sb = kq ^ ((n >> 1) & 3);
        short8 bf = *(const short8*)&Bchk[n * 32 + sb * 8];
        a2[nt] = __builtin_amdgcn_mfma_f32_16x16x32_bf16(af, bf, a2[nt], 0, 0, 0);
      }
    }
#pragma unroll
    for (int nt = 0; nt < 16; ++nt) {
#pragma unroll
      for (int r = 0; r < 4; ++r) {
        int row = m0 + w * 16 + cq * 4 + r;
        int cg  = p * 256 + nt * 16 + cl;
        qkvb[(size_t)row * 768 + cg] = f2bf(a2[nt][r] + bqk[cg]);
      }
    }
  }
}

// ================= MFMA banded attention (unchanged — verified) =================
#define KPAD 136
#define VPAD 184
#define PPAD 132
#define UNION 176

__global__ __launch_bounds__(256) void k_attn_mfma(const unsigned short* __restrict__ qkv,
                                                   unsigned short* __restrict__ ctx) {
  __shared__ __align__(16) unsigned short KV[UNION * KPAD];
  __shared__ __align__(16) unsigned short Ps[4][16 * PPAD];
  const int tid  = threadIdx.x;
  const int lane = tid & 63;
  const int w    = tid >> 6;
  const int i0   = blockIdx.x * 64;
  const int b    = blockIdx.y;
  const int h    = blockIdx.z;
  const int jmin_u = i0 - WIN;
  const float scale = 0.08838834764831845f;

  const int qrow = i0 + w * 16 + (lane & 15);
  const unsigned short* qptr =
      qkv + (size_t)(b * SLEN + min(qrow, SLEN - 1)) * 768 + h * 128 + (lane >> 4) * 8;
  short8 qf[4];
#pragma unroll
  for (int kc = 0; kc < 4; ++kc) qf[kc] = *(const short8*)(qptr + kc * 32);

  for (int it = 0; it < 11; ++it) {
    int idx = it * 256 + tid;
    int row = idx >> 4;
    int c8  = idx & 15;
    int j = jmin_u + row;
    uint4 v = make_uint4(0u, 0u, 0u, 0u);
    if (j >= 0 && j < SLEN)
      v = *(const uint4*)(qkv + (size_t)(b * SLEN + j) * 768 + 256 + h * 128 + c8 * 8);
    *(uint4*)&KV[row * KPAD + c8 * 8] = v;
  }
  __syncthreads();

  const int koff = w * 16;
  floatx4 sc[8] = {};
#pragma unroll
  for (int kt = 0; kt < 8; ++kt) {
#pragma unroll
    for (int kc = 0; kc < 4; ++kc) {
      short8 kf = *(const short8*)&KV[(koff + kt * 16 + (lane & 15)) * KPAD
                                      + kc * 32 + (lane >> 4) * 8];
      sc[kt] = __builtin_amdgcn_mfma_f32_16x16x32_bf16(qf[kc], kf, sc[kt], 0, 0, 0);
    }
  }

  const int qme = i0 + w * 16 + (lane >> 4) * 4;
  const int jme = jmin_u + koff + (lane & 15);
  float mx[4] = {-1e30f, -1e30f, -1e30f, -1e30f};
#pragma unroll
  for (int kt = 0; kt < 8; ++kt) {
#pragma unroll
    for (int r = 0; r < 4; ++r) {
      int j = jme + kt * 16, q = qme + r;
      bool ok = (j >= 0) && (j >= q - WIN) && (j <= q);
      float s = ok ? sc[kt][r] : -1e30f;
      sc[kt][r] = s;
      mx[r] = fmaxf(mx[r], s);
    }
  }
#pragma unroll
  for (int r = 0; r < 4; ++r)
#pragma unroll
    for (int off = 8; off; off >>= 1) mx[r] = fmaxf(mx[r], __shfl_xor(mx[r], off, 16));

  float sum[4] = {0.f, 0.f, 0.f, 0.f};
#pragma unroll
  for (int kt = 0; kt < 8; ++kt)
#pragma unroll
    for (int r = 0; r < 4; ++r) {
      float e = __expf((sc[kt][r] - mx[r]) * scale);
      sc[kt][r] = e;
      sum[r] += e;
    }
#pragma unroll
  for (int r = 0; r < 4; ++r)
#pragma unroll
    for (int off = 8; off; off >>= 1) sum[r] += __shfl_xor(sum[r], off, 16);
  float rinv[4];
#pragma unroll
  for (int r = 0; r < 4; ++r) rinv[r] = 1.f / sum[r];

  unsigned short* pw = &Ps[w][0];
#pragma unroll
  for (int kt = 0; kt < 8; ++kt)
#pragma unroll
    for (int r = 0; r < 4; ++r)
      pw[((lane >> 4) * 4 + r) * PPAD + kt * 16 + (lane & 15)] = f2bf(sc[kt][r]);
  __syncthreads();

  for (int it = 0; it < 12; ++it) {
    int idx = it * 256 + tid;
    int grp = idx >> 6;
    int key = (grp >> 4) * 64 + (idx & 63);
    int c8  = grp & 15;
    if (key < UNION) {
      int j = jmin_u + key;
      uint4 v = make_uint4(0u, 0u, 0u, 0u);
      if (j >= 0 && j < SLEN)
        v = *(const uint4*)(qkv + (size_t)(b * SLEN + j) * 768 + 512 + h * 128 + c8 * 8);
      unsigned short e[8];
      *(uint4*)e = v;
      int d0 = c8 * 8;
#pragma unroll
      for (int i = 0; i < 8; ++i) KV[(d0 + i) * VPAD + key] = e[i];
    }
  }
  __syncthreads();

  floatx4 ov[8] = {};
#pragma unroll
  for (int kc = 0; kc < 4; ++kc) {
    short8 pf = *(const short8*)&pw[(lane & 15) * PPAD + kc * 32 + (lane >> 4) * 8];
#pragma unroll
    for (int dt = 0; dt < 8; ++dt) {
      short8 vf = *(const short8*)&KV[(dt * 16 + (lane & 15)) * VPAD
                                      + koff + kc * 32 + (lane >> 4) * 8];
      ov[dt] = __builtin_amdgcn_mfma_f32_16x16x32_bf16(pf, vf, ov[dt], 0, 0, 0);
    }
  }

#pragma unroll
  for (int dt = 0; dt < 8; ++dt)
#pragma unroll
    for (int r = 0; r < 4; ++r) {
      int q = qme + r;
      if (q < SLEN)
        ctx[(size_t)(b * SLEN + q) * 256 + h * 128 + dt * 16 + (lane & 15)] =
            f2bf(ov[dt][r] * rinv[r]);
    }
}

// ================= fused post-attention chain (unchanged from R6 — verified) =================
__global__ __launch_bounds__(256) void k_post(
    const unsigned short* __restrict__ ctx,
    const unsigned short* __restrict__ wout, const float* __restrict__ bout,
    const unsigned short* __restrict__ xb,
    const float* __restrict__ ln1w, const float* __restrict__ ln1b,
    const unsigned short* __restrict__ w1, const float* __restrict__ b1,
    const unsigned short* __restrict__ w2, const float* __restrict__ b2,
    const float* __restrict__ hp, float* __restrict__ out) {
  __shared__ __align__(16) unsigned short X1[64 * XPAD];     // x1, then h
  __shared__ __align__(16) unsigned short Achk[64 * 32];
  __shared__ __align__(16) unsigned short Bchk[256 * 32];
  __shared__ float lnp[512];
  __shared__ float c1s[256];
  const int tid = threadIdx.x, lane = tid & 63, w = tid >> 6;
  const int m0 = blockIdx.x * 64;
  const int kq = lane >> 4, ml = lane & 15;
  const int myrow = w * 16 + ml;
  const int cq = lane >> 4, cl = lane & 15;

  lnp[tid] = ln1w[tid];
  lnp[256 + tid] = ln1b[tid];
  c1s[tid] = hp[tid];
  const float c0 = hp[256], sc1 = hp[257];

  int brow[4], bsc[4];
#pragma unroll
  for (int i = 0; i < 4; ++i) {
    brow[i] = (w * 4 + i) * 16 + (lane >> 2);
    bsc[i]  = (lane & 3) ^ ((brow[i] >> 1) & 3);
  }
  const int arow = w * 16 + (lane >> 2);            // A-chunk staging row
  const int asc  = (lane & 3) ^ ((arow >> 1) & 3);
  const unsigned short* actx = ctx + (size_t)(m0 + arow) * 256 + asc * 8;

  // ---- stage A: ctx @ Wout^T ----
  floatx4 acc[16] = {};
  for (int kt = 0; kt < 256; kt += 32) {
    __syncthreads();
    gload_lds16(actx + kt, &Achk[w * 512]);
#pragma unroll
    for (int i = 0; i < 4; ++i)
      gload_lds16(wout + (size_t)brow[i] * 256 + kt + bsc[i] * 8, &Bchk[(w * 4 + i) * 512]);
    __syncthreads();
    int sa = kq ^ ((myrow >> 1) & 3);
    short8 af = *(const short8*)&Achk[myrow * 32 + sa * 8];
#pragma unroll
    for (int nt = 0; nt < 16; ++nt) {
      int n = nt * 16 + ml;
      int sb = kq ^ ((n >> 1) & 3);
      short8 bf = *(const short8*)&Bchk[n * 32 + sb * 8];
      acc[nt] = __builtin_amdgcn_mfma_f32_16x16x32_bf16(af, bf, acc[nt], 0, 0, 0);
    }
  }
  // epilogue A: + bout + x residual; LN1 stats per row (in-wave)
  float s_[4] = {0.f, 0.f, 0.f, 0.f}, q_[4] = {0.f, 0.f, 0.f, 0.f};
#pragma unroll
  for (int nt = 0; nt < 16; ++nt) {
#pragma unroll
    for (int r = 0; r < 4; ++r) {
      int row = m0 + w * 16 + cq * 4 + r;
      int col = nt * 16 + cl;
      float v = acc[nt][r] + bout[col] + bf2f(xb[(size_t)row * 256 + col]);
      acc[nt][r] = v;
      s_[r] += v;
      q_[r] += v * v;
    }
  }
#pragma unroll
  for (int r = 0; r < 4; ++r)
#pragma unroll
    for (int off = 8; off; off >>= 1) {
      s_[r] += __shfl_xor(s_[r], off, 16);
      q_[r] += __shfl_xor(q_[r], off, 16);
    }
  floatx4 x1sav[16];
#pragma unroll
  for (int r = 0; r < 4; ++r) {
    float mu  = s_[r] * (1.f / 256.f);
    float var = q_[r] * (1.f / 256.f) - mu * mu;
    float rr  = rsqrtf(var + 1e-5f);
    int lrow  = w * 16 + cq * 4 + r;
#pragma unroll
    for (int nt = 0; nt < 16; ++nt) {
      int col = nt * 16 + cl;
      float x1 = (acc[nt][r] - mu) * rr * lnp[col] + lnp[256 + col];
      x1sav[nt][r] = x1;
      X1[lrow * XPAD + col] = f2bf(x1);
    }
  }

  // ---- stage B: h = relu(x1 @ W1^T + b1) ----
#pragma unroll
  for (int nt = 0; nt < 16; ++nt) acc[nt] = (floatx4){0.f, 0.f, 0.f, 0.f};
  for (int kt = 0; kt < 256; kt += 32) {
    __syncthreads();
#pragma unroll
    for (int i = 0; i < 4; ++i)
      gload_lds16(w1 + (size_t)brow[i] * 256 + kt + bsc[i] * 8, &Bchk[(w * 4 + i) * 512]);
    __syncthreads();
    short8 af = *(const short8*)&X1[myrow * XPAD + kt + kq * 8];
#pragma unroll
    for (int nt = 0; nt < 16; ++nt) {
      int n = nt * 16 + ml;
      int sb = kq ^ ((n >> 1) & 3);
      short8 bf = *(const short8*)&Bchk[n * 32 + sb * 8];
      acc[nt] = __builtin_amdgcn_mfma_f32_16x16x32_bf16(af, bf, acc[nt], 0, 0, 0);
    }
  }
  __syncthreads();   // all waves done reading x1 from X1
#pragma unroll
  for (int nt = 0; nt < 16; ++nt) {
#pragma unroll
    for (int r = 0; r < 4; ++r) {
      int lrow = w * 16 + cq * 4 + r;
      int col  = nt * 16 + cl;
      X1[lrow * XPAD + col] = f2bf(fmaxf(acc[nt][r] + b1[col], 0.f));
    }
  }
  __syncthreads();

  // ---- stage C: o = h @ W2^T + b2 + x1; LN2 + head ----
#pragma unroll
  for (int nt = 0; nt < 16; ++nt) acc[nt] = (floatx4){0.f, 0.f, 0.f, 0.f};
  for (int kt = 0; kt < 256; kt += 32) {
    __syncthreads();
#pragma unroll
    for (int i = 0; i < 4; ++i)
      gload_lds16(w2 + (size_t)brow[i] * 256 + kt + bsc[i] * 8, &Bchk[(w * 4 + i) * 512]);
    __syncthreads();
    short8 af = *(const short8*)&X1[myrow * XPAD + kt + kq * 8];
#pragma unroll
    for (int nt = 0; nt < 16; ++nt) {
      int n = nt * 16 + ml;
      int sb = kq ^ ((n >> 1) & 3);
      short8 bf = *(const short8*)&Bchk[n * 32 + sb * 8];
      acc[nt] = __builtin_amdgcn_mfma_f32_16x16x32_bf16(af, bf, acc[nt], 0, 0, 0);
    }
  }
  float ss[4] = {0.f, 0.f, 0.f, 0.f}, qq[4] = {0.f, 0.f, 0.f, 0.f}, dd[4] = {0.f, 0.f, 0.f, 0.f};
#pragma unroll
  for (int nt = 0; nt < 16; ++nt) {
#pragma unroll
    for (int r = 0; r < 4; ++r) {
      int col = nt * 16 + cl;
      float v = acc[nt][r] + b2[col] + x1sav[nt][r];
      ss[r] += v;
      qq[r] += v * v;
      dd[r] += v * c1s[col];
    }
  }
#pragma unroll
  for (int r = 0; r < 4; ++r)
#pragma unroll
    for (int off = 8; off; off >>= 1) {
      ss[r] += __shfl_xor(ss[r], off, 16);
      qq[r] += __shfl_xor(qq[r], off, 16);
      dd[r] += __shfl_xor(dd[r], off, 16);
    }
  if (cl == 0) {
#pragma unroll
    for (int r = 0; r < 4; ++r) {
      float mu  = ss[r] * (1.f / 256.f);
      float var = qq[r] * (1.f / 256.f) - mu * mu;
      float rr  = rsqrtf(var + 1e-5f);
      out[m0 + w * 16 + cq * 4 + r] = rr * (dd[r] - mu * sc1) + c0;
    }
  }
}

extern "C" void kernel_launch(void* const* d_in, const int* in_sizes, int n_in,
                              void* d_out, int out_size, void* d_ws, size_t ws_size,
                              hipStream_t stream) {
  const float* src        = (const float*)d_in[0];
  // d_in[1] = input_lengths (unused)
  const float* W_enc      = (const float*)d_in[2];
  const float* b_enc      = (const float*)d_in[3];
  const float* in_proj_w  = (const float*)d_in[4];
  const float* in_proj_b  = (const float*)d_in[5];
  const float* out_proj_w = (const float*)d_in[6];
  const float* out_proj_b = (const float*)d_in[7];
  const float* ln1_w      = (const float*)d_in[8];
  const float* ln1_b      = (const float*)d_in[9];
  const float* lin1_w     = (const float*)d_in[10];
  const float* lin1_b     = (const float*)d_in[11];
  const float* lin2_w     = (const float*)d_in[12];
  const float* lin2_b     = (const float*)d_in[13];
  const float* ln2_w      = (const float*)d_in[14];
  const float* ln2_b      = (const float*)d_in[15];
  const float* fc1_w      = (const float*)d_in[16];
  const float* fc1_b      = (const float*)d_in[17];
  const float* fc2_w      = (const float*)d_in[18];
  const float* fc2_b      = (const float*)d_in[19];

  char* p = (char*)d_ws;
  float* pe            = (float*)p;           p += (size_t)SLEN * 256 * 4;
  float* hp            = (float*)p;           p += 2048;   // 258 floats used
  unsigned short* xb   = (unsigned short*)p;  p += (size_t)MTOK * 256 * 2;
  unsigned short* qkvb = (unsigned short*)p;  p += (size_t)MTOK * 768 * 2;
  unsigned short* ctxb = (unsigned short*)p;  p += (size_t)MTOK * 256 * 2;
  unsigned short* wencb= (unsigned short*)p;  p += 256 * 256 * 2;
  unsigned short* wqkb = (unsigned short*)p;  p += 768 * 256 * 2;
  unsigned short* woutb= (unsigned short*)p;  p += 256 * 256 * 2;
  unsigned short* wl1b = (unsigned short*)p;  p += 256 * 256 * 2;
  unsigned short* wl2b = (unsigned short*)p;  p += 256 * 256 * 2;

  // prep: 5 weight cvts (448) + posenc (500, float4) + headprep (1)
  k_prep<<<949, 256, 0, stream>>>(W_enc, wencb, in_proj_w, wqkb,
                                  out_proj_w, woutb, lin1_w, wl1b, lin2_w, wl2b,
                                  pe, fc1_w, fc1_b, fc2_w, fc2_b, ln2_w, ln2_b, hp);
  // fused encoder + qkv, column-split for 2 blocks/CU
  k_pre<<<dim3(MTOK / 64, 2), 256, 0, stream>>>(src, wencb, b_enc, pe, wqkb, in_proj_b, xb, qkvb);
  // banded attention (MFMA)
  k_attn_mfma<<<dim3((SLEN + 63) / 64, BATCH, 2), 256, 0, stream>>>(qkvb, ctxb);
  // fused out_proj + LN1 + FFN + LN2 + head
  k_post<<<MTOK / 64, 256, 0, stream>>>(ctxb, woutb, out_proj_b, xb, ln1_w, ln1_b,
                                        wl1b, lin1_b, wl2b, lin2_b, hp, (float*)d_out);
}

// Round 9
// 173.532 us; speedup vs baseline: 1.8629x; 1.0480x over previous
//
#include <hip/hip_runtime.h>
#include <math.h>

#define SLEN 2000
#define BATCH 8
#define MTOK 16000
#define WIN 99
#define XPAD 264

typedef __attribute__((ext_vector_type(8))) short short8;
typedef __attribute__((ext_vector_type(4))) float floatx4;

// s_waitcnt imm (gfx9 family): vmcnt[3:0]=bits[3:0], vmcnt[5:4]=bits[15:14],
// expcnt=bits[6:4], lgkmcnt=bits[11:8]. 0x0F70 = exp/lgkm unconstrained, vmcnt(0).
#define WAITVM0() __builtin_amdgcn_s_waitcnt(0x0F70)
#define WAITVM4() __builtin_amdgcn_s_waitcnt(0x0F74)

// ---------- bf16 helpers (bit-level, RNE) ----------
__device__ __forceinline__ float bf2f(unsigned int h) {
  union { unsigned int u; float f; } w; w.u = h << 16; return w.f;
}
__device__ __forceinline__ unsigned short f2bf(float f) {
  union { float f; unsigned int u; } w; w.f = f;
  return (unsigned short)((w.u + 0x7fffu + ((w.u >> 16) & 1u)) >> 16);
}

// async global->LDS, 16B per lane; lds base must be wave-uniform
typedef const __attribute__((address_space(1))) unsigned int* gas_t;
typedef __attribute__((address_space(3))) unsigned int* las_t;
__device__ __forceinline__ void gload_lds16(const unsigned short* g, unsigned short* l) {
  __builtin_amdgcn_global_load_lds((gas_t)g, (las_t)l, 16, 0, 0);
}

// ================= prep: 5 weight cvts + posenc + headprep (unchanged R8) =================
__device__ __forceinline__ void cvt4(const float* __restrict__ in,
                                     unsigned short* __restrict__ out, int i) {
  float4 v = ((const float4*)in)[i];
  ushort4 o;
  o.x = f2bf(v.x); o.y = f2bf(v.y); o.z = f2bf(v.z); o.w = f2bf(v.w);
  ((ushort4*)out)[i] = o;
}

__global__ __launch_bounds__(256) void k_prep(
    const float* __restrict__ wenc,     unsigned short* __restrict__ wencb,
    const float* __restrict__ wqk,      unsigned short* __restrict__ wqkb,
    const float* __restrict__ wout,     unsigned short* __restrict__ woutb,
    const float* __restrict__ wl1,      unsigned short* __restrict__ wl1b,
    const float* __restrict__ wl2,      unsigned short* __restrict__ wl2b,
    float* __restrict__ pe,
    const float* __restrict__ fc1w, const float* __restrict__ fc1b,
    const float* __restrict__ fc2w, const float* __restrict__ fc2b,
    const float* __restrict__ ln2w, const float* __restrict__ ln2b,
    float* __restrict__ hp) {
  __shared__ float red0[4], red1[4];
  const int bx = blockIdx.x, tid = threadIdx.x;
  if (bx < 64)         { cvt4(wenc, wencb, bx * 256 + tid); }
  else if (bx < 256)   { cvt4(wqk,  wqkb,  (bx - 64) * 256 + tid); }
  else if (bx < 320)   { cvt4(wout, woutb, (bx - 256) * 256 + tid); }
  else if (bx < 384)   { cvt4(wl1,  wl1b,  (bx - 320) * 256 + tid); }
  else if (bx < 448)   { cvt4(wl2,  wl2b,  (bx - 384) * 256 + tid); }
  else if (bx < 948) {                                       // posenc, float4/thread
    int i4 = (bx - 448) * 256 + tid;
    int e0 = i4 * 4;
    int s  = e0 >> 8;
    int d0 = e0 & 255;
    float dv0 = expf((float)(d0 >> 1) * -0.07195578415606394f);
    float dv1 = expf((float)((d0 >> 1) + 1) * -0.07195578415606394f);
    float a0 = (float)s * dv0, a1 = (float)s * dv1;
    ((float4*)pe)[i4] = make_float4(sinf(a0), cosf(a0), sinf(a1), cosf(a1));
  } else {                                                   // headprep (1 block)
    int k = tid;
    float we = 0.f;
#pragma unroll 8
    for (int o = 0; o < 64; ++o) we += fc2w[o] * fc1w[o * 256 + k];
    float c1 = ln2w[k] * we;
    hp[k] = c1;
    float p0 = ln2b[k] * we;
    if (k < 64) p0 += fc2w[k] * fc1b[k];
    float s0 = p0, s1 = c1;
#pragma unroll
    for (int off = 32; off; off >>= 1) {
      s0 += __shfl_xor(s0, off);
      s1 += __shfl_xor(s1, off);
    }
    int wv = k >> 6;
    if ((k & 63) == 0) { red0[wv] = s0; red1[wv] = s1; }
    __syncthreads();
    if (k == 0) {
      hp[256] = red0[0] + red0[1] + red0[2] + red0[3] + fc2b[0];
      hp[257] = red1[0] + red1[1] + red1[2] + red1[3];
    }
  }
}

// ================= fused encoder + qkv — BARRIER-FREE K-loops =================
// 250 blocks x 64 tokens. Wave w owns all 64 rows x cols [64w,64w+64).
// B slices are wave-private LDS (no cross-wave deps -> no __syncthreads in
// K-loops). Stage 1: A (src fp32) read direct from global + in-reg cvt,
// B single-depth with explicit vmcnt(0). Stage 2: A (x) from LDS Xt, B
// prefetched 2-deep with manual s_waitcnt vmcnt(4) (in-order semantics).
__global__ __launch_bounds__(256) void k_pre(
    const float* __restrict__ src,
    const unsigned short* __restrict__ wenc, const float* __restrict__ benc,
    const float* __restrict__ pe,
    const unsigned short* __restrict__ wqk, const float* __restrict__ bqk,
    unsigned short* __restrict__ xb, unsigned short* __restrict__ qkvb) {
  __shared__ __align__(16) unsigned short Xt[64 * XPAD];       // 33792 B
  __shared__ __align__(16) unsigned short Bst[4][2][2048];     // 32768 B
  const int tid = threadIdx.x, lane = tid & 63, w = tid >> 6;
  const int m0 = blockIdx.x * 64;
  const int kq = lane >> 4, ml = lane & 15;
  const int wcolg = w * 64;                    // wave's global col base

  int grow[4], gsc[4];
#pragma unroll
  for (int i = 0; i < 4; ++i) {
    grow[i] = i * 16 + (lane >> 2);
    gsc[i]  = (lane & 3) ^ ((grow[i] >> 1) & 3);
  }

  auto issueB = [&](const unsigned short* W, int kt, int buf) {
#pragma unroll
    for (int i = 0; i < 4; ++i)
      gload_lds16(W + (size_t)(wcolg + grow[i]) * 256 + kt + gsc[i] * 8,
                  &Bst[w][buf][i * 512]);
  };
  auto readB = [&](int buf, int nt) -> short8 {
    int n = nt * 16 + ml;
    int sb = kq ^ ((n >> 1) & 3);
    return *(const short8*)&Bst[w][buf][n * 32 + sb * 8];
  };

  // ---- stage 1: x = src @ Wenc^T (single-depth B, alternating bufs) ----
  floatx4 acc[4][4] = {};
#pragma unroll
  for (int k8 = 0; k8 < 8; ++k8) {
    const int kt = k8 * 32;
    issueB(wenc, kt, k8 & 1);
    short8 af[4];
#pragma unroll
    for (int mt = 0; mt < 4; ++mt) {
      const float* ap = src + (size_t)(m0 + mt * 16 + ml) * 256 + kt + kq * 8;
      float4 v0 = *(const float4*)ap;
      float4 v1 = *(const float4*)(ap + 4);
      unsigned short t8[8] = {f2bf(v0.x), f2bf(v0.y), f2bf(v0.z), f2bf(v0.w),
                              f2bf(v1.x), f2bf(v1.y), f2bf(v1.z), f2bf(v1.w)};
      af[mt] = *(const short8*)t8;
    }
    WAITVM0();
#pragma unroll
    for (int nt = 0; nt < 4; ++nt) {
      short8 bf = readB(k8 & 1, nt);
#pragma unroll
      for (int mt = 0; mt < 4; ++mt)
        acc[mt][nt] = __builtin_amdgcn_mfma_f32_16x16x32_bf16(af[mt], bf, acc[mt][nt], 0, 0, 0);
    }
  }
  // epilogue -> Xt (LDS) + xb (global)
#pragma unroll
  for (int mt = 0; mt < 4; ++mt)
#pragma unroll
    for (int nt = 0; nt < 4; ++nt)
#pragma unroll
      for (int r = 0; r < 4; ++r) {
        int lrow = mt * 16 + kq * 4 + r;
        int col  = wcolg + nt * 16 + ml;
        float v = acc[mt][nt][r] + benc[col]
                + pe[(size_t)((m0 + lrow) % SLEN) * 256 + col];
        unsigned short hv = f2bf(v);
        Xt[lrow * XPAD + col] = hv;
        xb[(size_t)(m0 + lrow) * 256 + col] = hv;
      }
  __syncthreads();

  // ---- stage 2: qkv = Xt @ Wqk^T, 3 passes, 2-deep B prefetch ----
  for (int p = 0; p < 3; ++p) {
    const unsigned short* Wp = wqk + (size_t)p * 65536;
    floatx4 a2[4][4] = {};
    issueB(Wp, 0, 0);
#pragma unroll
    for (int k8 = 0; k8 < 7; ++k8) {
      issueB(Wp, (k8 + 1) * 32, (k8 + 1) & 1);
      WAITVM4();
      short8 af[4];
#pragma unroll
      for (int mt = 0; mt < 4; ++mt)
        af[mt] = *(const short8*)&Xt[(mt * 16 + ml) * XPAD + k8 * 32 + kq * 8];
#pragma unroll
      for (int nt = 0; nt < 4; ++nt) {
        short8 bf = readB(k8 & 1, nt);
#pragma unroll
        for (int mt = 0; mt < 4; ++mt)
          a2[mt][nt] = __builtin_amdgcn_mfma_f32_16x16x32_bf16(af[mt], bf, a2[mt][nt], 0, 0, 0);
      }
    }
    WAITVM0();
    {
      short8 af[4];
#pragma unroll
      for (int mt = 0; mt < 4; ++mt)
        af[mt] = *(const short8*)&Xt[(mt * 16 + ml) * XPAD + 224 + kq * 8];
#pragma unroll
      for (int nt = 0; nt < 4; ++nt) {
        short8 bf = readB(1, nt);
#pragma unroll
        for (int mt = 0; mt < 4; ++mt)
          a2[mt][nt] = __builtin_amdgcn_mfma_f32_16x16x32_bf16(af[mt], bf, a2[mt][nt], 0, 0, 0);
      }
    }
#pragma unroll
    for (int mt = 0; mt < 4; ++mt)
#pragma unroll
      for (int nt = 0; nt < 4; ++nt)
#pragma unroll
        for (int r = 0; r < 4; ++r) {
          int row = m0 + mt * 16 + kq * 4 + r;
          int cg  = p * 256 + wcolg + nt * 16 + ml;
          qkvb[(size_t)row * 768 + cg] = f2bf(a2[mt][nt][r] + bqk[cg]);
        }
  }
}

// ================= MFMA banded attention (unchanged — verified) =================
#define KPAD 136
#define VPAD 184
#define PPAD 132
#define UNION 176

__global__ __launch_bounds__(256) void k_attn_mfma(const unsigned short* __restrict__ qkv,
                                                   unsigned short* __restrict__ ctx) {
  __shared__ __align__(16) unsigned short KV[UNION * KPAD];
  __shared__ __align__(16) unsigned short Ps[4][16 * PPAD];
  const int tid  = threadIdx.x;
  const int lane = tid & 63;
  const int w    = tid >> 6;
  const int i0   = blockIdx.x * 64;
  const int b    = blockIdx.y;
  const int h    = blockIdx.z;
  const int jmin_u = i0 - WIN;
  const float scale = 0.08838834764831845f;

  const int qrow = i0 + w * 16 + (lane & 15);
  const unsigned short* qptr =
      qkv + (size_t)(b * SLEN + min(qrow, SLEN - 1)) * 768 + h * 128 + (lane >> 4) * 8;
  short8 qf[4];
#pragma unroll
  for (int kc = 0; kc < 4; ++kc) qf[kc] = *(const short8*)(qptr + kc * 32);

  for (int it = 0; it < 11; ++it) {
    int idx = it * 256 + tid;
    int row = idx >> 4;
    int c8  = idx & 15;
    int j = jmin_u + row;
    uint4 v = make_uint4(0u, 0u, 0u, 0u);
    if (j >= 0 && j < SLEN)
      v = *(const uint4*)(qkv + (size_t)(b * SLEN + j) * 768 + 256 + h * 128 + c8 * 8);
    *(uint4*)&KV[row * KPAD + c8 * 8] = v;
  }
  __syncthreads();

  const int koff = w * 16;
  floatx4 sc[8] = {};
#pragma unroll
  for (int kt = 0; kt < 8; ++kt) {
#pragma unroll
    for (int kc = 0; kc < 4; ++kc) {
      short8 kf = *(const short8*)&KV[(koff + kt * 16 + (lane & 15)) * KPAD
                                      + kc * 32 + (lane >> 4) * 8];
      sc[kt] = __builtin_amdgcn_mfma_f32_16x16x32_bf16(qf[kc], kf, sc[kt], 0, 0, 0);
    }
  }

  const int qme = i0 + w * 16 + (lane >> 4) * 4;
  const int jme = jmin_u + koff + (lane & 15);
  float mx[4] = {-1e30f, -1e30f, -1e30f, -1e30f};
#pragma unroll
  for (int kt = 0; kt < 8; ++kt) {
#pragma unroll
    for (int r = 0; r < 4; ++r) {
      int j = jme + kt * 16, q = qme + r;
      bool ok = (j >= 0) && (j >= q - WIN) && (j <= q);
      float s = ok ? sc[kt][r] : -1e30f;
      sc[kt][r] = s;
      mx[r] = fmaxf(mx[r], s);
    }
  }
#pragma unroll
  for (int r = 0; r < 4; ++r)
#pragma unroll
    for (int off = 8; off; off >>= 1) mx[r] = fmaxf(mx[r], __shfl_xor(mx[r], off, 16));

  float sum[4] = {0.f, 0.f, 0.f, 0.f};
#pragma unroll
  for (int kt = 0; kt < 8; ++kt)
#pragma unroll
    for (int r = 0; r < 4; ++r) {
      float e = __expf((sc[kt][r] - mx[r]) * scale);
      sc[kt][r] = e;
      sum[r] += e;
    }
#pragma unroll
  for (int r = 0; r < 4; ++r)
#pragma unroll
    for (int off = 8; off; off >>= 1) sum[r] += __shfl_xor(sum[r], off, 16);
  float rinv[4];
#pragma unroll
  for (int r = 0; r < 4; ++r) rinv[r] = 1.f / sum[r];

  unsigned short* pw = &Ps[w][0];
#pragma unroll
  for (int kt = 0; kt < 8; ++kt)
#pragma unroll
    for (int r = 0; r < 4; ++r)
      pw[((lane >> 4) * 4 + r) * PPAD + kt * 16 + (lane & 15)] = f2bf(sc[kt][r]);
  __syncthreads();

  for (int it = 0; it < 12; ++it) {
    int idx = it * 256 + tid;
    int grp = idx >> 6;
    int key = (grp >> 4) * 64 + (idx & 63);
    int c8  = grp & 15;
    if (key < UNION) {
      int j = jmin_u + key;
      uint4 v = make_uint4(0u, 0u, 0u, 0u);
      if (j >= 0 && j < SLEN)
        v = *(const uint4*)(qkv + (size_t)(b * SLEN + j) * 768 + 512 + h * 128 + c8 * 8);
      unsigned short e[8];
      *(uint4*)e = v;
      int d0 = c8 * 8;
#pragma unroll
      for (int i = 0; i < 8; ++i) KV[(d0 + i) * VPAD + key] = e[i];
    }
  }
  __syncthreads();

  floatx4 ov[8] = {};
#pragma unroll
  for (int kc = 0; kc < 4; ++kc) {
    short8 pf = *(const short8*)&pw[(lane & 15) * PPAD + kc * 32 + (lane >> 4) * 8];
#pragma unroll
    for (int dt = 0; dt < 8; ++dt) {
      short8 vf = *(const short8*)&KV[(dt * 16 + (lane & 15)) * VPAD
                                      + koff + kc * 32 + (lane >> 4) * 8];
      ov[dt] = __builtin_amdgcn_mfma_f32_16x16x32_bf16(pf, vf, ov[dt], 0, 0, 0);
    }
  }

#pragma unroll
  for (int dt = 0; dt < 8; ++dt)
#pragma unroll
    for (int r = 0; r < 4; ++r) {
      int q = qme + r;
      if (q < SLEN)
        ctx[(size_t)(b * SLEN + q) * 256 + h * 128 + dt * 16 + (lane & 15)] =
            f2bf(ov[dt][r] * rinv[r]);
    }
}

// ================= fused post chain — BARRIER-FREE K-loops =================
// 250 blocks x 64 tokens; wave w owns all 64 rows x cols [64w,64w+64).
// Stage A: ctx@Wout^T (+bout+x) -> LN1 (cross-wave partials) -> x1 (X1 + regs)
// Stage B: relu(x1@W1^T+b1) -> h overwrites X1  (2-deep B prefetch)
// Stage C: h@W2^T (+b2+x1)  -> LN2 + collapsed head -> logits
__global__ __launch_bounds__(256) void k_post(
    const unsigned short* __restrict__ ctx,
    const unsigned short* __restrict__ wout, const float* __restrict__ bout,
    const unsigned short* __restrict__ xb,
    const float* __restrict__ ln1w, const float* __restrict__ ln1b,
    const unsigned short* __restrict__ w1, const float* __restrict__ b1,
    const unsigned short* __restrict__ w2, const float* __restrict__ b2,
    const float* __restrict__ hp, float* __restrict__ out) {
  __shared__ __align__(16) unsigned short X1[64 * XPAD];       // x1, then h
  __shared__ __align__(16) unsigned short Bst[4][2][2048];
  __shared__ float lnred[4][64][3];
  __shared__ float lnstat[64][2];
  __shared__ float lnp[512];
  __shared__ float c1s[256];
  const int tid = threadIdx.x, lane = tid & 63, w = tid >> 6;
  const int m0 = blockIdx.x * 64;
  const int kq = lane >> 4, ml = lane & 15;
  const int wcolg = w * 64;

  lnp[tid] = ln1w[tid];
  lnp[256 + tid] = ln1b[tid];
  c1s[tid] = hp[tid];
  const float c0h = hp[256], sc1 = hp[257];

  int grow[4], gsc[4];
#pragma unroll
  for (int i = 0; i < 4; ++i) {
    grow[i] = i * 16 + (lane >> 2);
    gsc[i]  = (lane & 3) ^ ((grow[i] >> 1) & 3);
  }
  auto issueB = [&](const unsigned short* W, int kt, int buf) {
#pragma unroll
    for (int i = 0; i < 4; ++i)
      gload_lds16(W + (size_t)(wcolg + grow[i]) * 256 + kt + gsc[i] * 8,
                  &Bst[w][buf][i * 512]);
  };
  auto readB = [&](int buf, int nt) -> short8 {
    int n = nt * 16 + ml;
    int sb = kq ^ ((n >> 1) & 3);
    return *(const short8*)&Bst[w][buf][n * 32 + sb * 8];
  };

  // ---- stage A: ctx @ Wout^T (A direct from global, single-depth B) ----
  floatx4 acc[4][4] = {};
#pragma unroll
  for (int k8 = 0; k8 < 8; ++k8) {
    const int kt = k8 * 32;
    issueB(wout, kt, k8 & 1);
    short8 af[4];
#pragma unroll
    for (int mt = 0; mt < 4; ++mt)
      af[mt] = *(const short8*)(ctx + (size_t)(m0 + mt * 16 + ml) * 256 + kt + kq * 8);
    WAITVM0();
#pragma unroll
    for (int nt = 0; nt < 4; ++nt) {
      short8 bf = readB(k8 & 1, nt);
#pragma unroll
      for (int mt = 0; mt < 4; ++mt)
        acc[mt][nt] = __builtin_amdgcn_mfma_f32_16x16x32_bf16(af[mt], bf, acc[mt][nt], 0, 0, 0);
    }
  }
  // + bout + x residual; LN1 via cross-wave partials
  float s_[4][4], q_[4][4];   // [mt][r] row partials over this wave's 64 cols
#pragma unroll
  for (int mt = 0; mt < 4; ++mt)
#pragma unroll
    for (int r = 0; r < 4; ++r) { s_[mt][r] = 0.f; q_[mt][r] = 0.f; }
#pragma unroll
  for (int mt = 0; mt < 4; ++mt)
#pragma unroll
    for (int nt = 0; nt < 4; ++nt)
#pragma unroll
      for (int r = 0; r < 4; ++r) {
        int lrow = mt * 16 + kq * 4 + r;
        int col  = wcolg + nt * 16 + ml;
        float v = acc[mt][nt][r] + bout[col]
                + bf2f(xb[(size_t)(m0 + lrow) * 256 + col]);
        acc[mt][nt][r] = v;
        s_[mt][r] += v;
        q_[mt][r] += v * v;
      }
#pragma unroll
  for (int mt = 0; mt < 4; ++mt)
#pragma unroll
    for (int r = 0; r < 4; ++r) {
#pragma unroll
      for (int off = 8; off; off >>= 1) {
        s_[mt][r] += __shfl_xor(s_[mt][r], off, 16);
        q_[mt][r] += __shfl_xor(q_[mt][r], off, 16);
      }
      if (ml == 0) {
        int lrow = mt * 16 + kq * 4 + r;
        lnred[w][lrow][0] = s_[mt][r];
        lnred[w][lrow][1] = q_[mt][r];
      }
    }
  __syncthreads();
  if (tid < 64) {
    float s = lnred[0][tid][0] + lnred[1][tid][0] + lnred[2][tid][0] + lnred[3][tid][0];
    float q = lnred[0][tid][1] + lnred[1][tid][1] + lnred[2][tid][1] + lnred[3][tid][1];
    float mu  = s * (1.f / 256.f);
    float var = q * (1.f / 256.f) - mu * mu;
    lnstat[tid][0] = mu;
    lnstat[tid][1] = rsqrtf(var + 1e-5f);
  }
  __syncthreads();
  floatx4 x1sav[4][4];
#pragma unroll
  for (int mt = 0; mt < 4; ++mt)
#pragma unroll
    for (int r = 0; r < 4; ++r) {
      int lrow = mt * 16 + kq * 4 + r;
      float mu = lnstat[lrow][0], rr = lnstat[lrow][1];
#pragma unroll
      for (int nt = 0; nt < 4; ++nt) {
        int col = wcolg + nt * 16 + ml;
        float x1 = (acc[mt][nt][r] - mu) * rr * lnp[col] + lnp[256 + col];
        x1sav[mt][nt][r] = x1;
        X1[lrow * XPAD + col] = f2bf(x1);
      }
    }
  __syncthreads();

  // ---- stage B: h = relu(x1 @ W1^T + b1), 2-deep prefetch ----
#pragma unroll
  for (int mt = 0; mt < 4; ++mt)
#pragma unroll
    for (int nt = 0; nt < 4; ++nt) acc[mt][nt] = (floatx4){0.f, 0.f, 0.f, 0.f};
  issueB(w1, 0, 0);
#pragma unroll
  for (int k8 = 0; k8 < 7; ++k8) {
    issueB(w1, (k8 + 1) * 32, (k8 + 1) & 1);
    WAITVM4();
    short8 af[4];
#pragma unroll
    for (int mt = 0; mt < 4; ++mt)
      af[mt] = *(const short8*)&X1[(mt * 16 + ml) * XPAD + k8 * 32 + kq * 8];
#pragma unroll
    for (int nt = 0; nt < 4; ++nt) {
      short8 bf = readB(k8 & 1, nt);
#pragma unroll
      for (int mt = 0; mt < 4; ++mt)
        acc[mt][nt] = __builtin_amdgcn_mfma_f32_16x16x32_bf16(af[mt], bf, acc[mt][nt], 0, 0, 0);
    }
  }
  WAITVM0();
  {
    short8 af[4];
#pragma unroll
    for (int mt = 0; mt < 4; ++mt)
      af[mt] = *(const short8*)&X1[(mt * 16 + ml) * XPAD + 224 + kq * 8];
#pragma unroll
    for (int nt = 0; nt < 4; ++nt) {
      short8 bf = readB(1, nt);
#pragma unroll
      for (int mt = 0; mt < 4; ++mt)
        acc[mt][nt] = __builtin_amdgcn_mfma_f32_16x16x32_bf16(af[mt], bf, acc[mt][nt], 0, 0, 0);
    }
  }
  __syncthreads();   // all waves done reading x1 before h overwrite
#pragma unroll
  for (int mt = 0; mt < 4; ++mt)
#pragma unroll
    for (int nt = 0; nt < 4; ++nt)
#pragma unroll
      for (int r = 0; r < 4; ++r) {
        int lrow = mt * 16 + kq * 4 + r;
        int col  = wcolg + nt * 16 + ml;
        X1[lrow * XPAD + col] = f2bf(fmaxf(acc[mt][nt][r] + b1[col], 0.f));
      }
  __syncthreads();

  // ---- stage C: o = h @ W2^T + b2 + x1 -> LN2 + collapsed head ----
#pragma unroll
  for (int mt = 0; mt < 4; ++mt)
#pragma unroll
    for (int nt = 0; nt < 4; ++nt) acc[mt][nt] = (floatx4){0.f, 0.f, 0.f, 0.f};
  issueB(w2, 0, 0);
#pragma unroll
  for (int k8 = 0; k8 < 7; ++k8) {
    issueB(w2, (k8 + 1) * 32, (k8 + 1) & 1);
    WAITVM4();
    short8 af[4];
#pragma unroll
    for (int mt = 0; mt < 4; ++mt)
      af[mt] = *(const short8*)&X1[(mt * 16 + ml) * XPAD + k8 * 32 + kq * 8];
#pragma unroll
    for (int nt = 0; nt < 4; ++nt) {
      short8 bf = readB(k8 & 1, nt);
#pragma unroll
      for (int mt = 0; mt < 4; ++mt)
        acc[mt][nt] = __builtin_amdgcn_mfma_f32_16x16x32_bf16(af[mt], bf, acc[mt][nt], 0, 0, 0);
    }
  }
  WAITVM0();
  {
    short8 af[4];
#pragma unroll
    for (int mt = 0; mt < 4; ++mt)
      af[mt] = *(const short8*)&X1[(mt * 16 + ml) * XPAD + 224 + kq * 8];
#pragma unroll
    for (int nt = 0; nt < 4; ++nt) {
      short8 bf = readB(1, nt);
#pragma unroll
      for (int mt = 0; mt < 4; ++mt)
        acc[mt][nt] = __builtin_amdgcn_mfma_f32_16x16x32_bf16(af[mt], bf, acc[mt][nt], 0, 0, 0);
    }
  }
  float ss[4][4], qq[4][4], dd[4][4];
#pragma unroll
  for (int mt = 0; mt < 4; ++mt)
#pragma unroll
    for (int r = 0; r < 4; ++r) { ss[mt][r] = 0.f; qq[mt][r] = 0.f; dd[mt][r] = 0.f; }
#pragma unroll
  for (int mt = 0; mt < 4; ++mt)
#pragma unroll
    for (int nt = 0; nt < 4; ++nt)
#pragma unroll
      for (int r = 0; r < 4; ++r) {
        int col = wcolg + nt * 16 + ml;
        float v = acc[mt][nt][r] + b2[col] + x1sav[mt][nt][r];
        ss[mt][r] += v;
        qq[mt][r] += v * v;
        dd[mt][r] += v * c1s[col];
      }
#pragma unroll
  for (int mt = 0; mt < 4; ++mt)
#pragma unroll
    for (int r = 0; r < 4; ++r) {
#pragma unroll
      for (int off = 8; off; off >>= 1) {
        ss[mt][r] += __shfl_xor(ss[mt][r], off, 16);
        qq[mt][r] += __shfl_xor(qq[mt][r], off, 16);
        dd[mt][r] += __shfl_xor(dd[mt][r], off, 16);
      }
      if (ml == 0) {
        int lrow = mt * 16 + kq * 4 + r;
        lnred[w][lrow][0] = ss[mt][r];
        lnred[w][lrow][1] = qq[mt][r];
        lnred[w][lrow][2] = dd[mt][r];
      }
    }
  __syncthreads();
  if (tid < 64) {
    float s = lnred[0][tid][0] + lnred[1][tid][0] + lnred[2][tid][0] + lnred[3][tid][0];
    float q = lnred[0][tid][1] + lnred[1][tid][1] + lnred[2][tid][1] + lnred[3][tid][1];
    float d = lnred[0][tid][2] + lnred[1][tid][2] + lnred[2][tid][2] + lnred[3][tid][2];
    float mu  = s * (1.f / 256.f);
    float var = q * (1.f / 256.f) - mu * mu;
    float rr  = rsqrtf(var + 1e-5f);
    out[m0 + tid] = rr * (d - mu * sc1) + c0h;
  }
}

extern "C" void kernel_launch(void* const* d_in, const int* in_sizes, int n_in,
                              void* d_out, int out_size, void* d_ws, size_t ws_size,
                              hipStream_t stream) {
  const float* src        = (const float*)d_in[0];
  // d_in[1] = input_lengths (unused)
  const float* W_enc      = (const float*)d_in[2];
  const float* b_enc      = (const float*)d_in[3];
  const float* in_proj_w  = (const float*)d_in[4];
  const float* in_proj_b  = (const float*)d_in[5];
  const float* out_proj_w = (const float*)d_in[6];
  const float* out_proj_b = (const float*)d_in[7];
  const float* ln1_w      = (const float*)d_in[8];
  const float* ln1_b      = (const float*)d_in[9];
  const float* lin1_w     = (const float*)d_in[10];
  const float* lin1_b     = (const float*)d_in[11];
  const float* lin2_w     = (const float*)d_in[12];
  const float* lin2_b     = (const float*)d_in[13];
  const float* ln2_w      = (const float*)d_in[14];
  const float* ln2_b      = (const float*)d_in[15];
  const float* fc1_w      = (const float*)d_in[16];
  const float* fc1_b      = (const float*)d_in[17];
  const float* fc2_w      = (const float*)d_in[18];
  const float* fc2_b      = (const float*)d_in[19];

  char* p = (char*)d_ws;
  float* pe            = (float*)p;           p += (size_t)SLEN * 256 * 4;
  float* hp            = (float*)p;           p += 2048;   // 258 floats used
  unsigned short* xb   = (unsigned short*)p;  p += (size_t)MTOK * 256 * 2;
  unsigned short* qkvb = (unsigned short*)p;  p += (size_t)MTOK * 768 * 2;
  unsigned short* ctxb = (unsigned short*)p;  p += (size_t)MTOK * 256 * 2;
  unsigned short* wencb= (unsigned short*)p;  p += 256 * 256 * 2;
  unsigned short* wqkb = (unsigned short*)p;  p += 768 * 256 * 2;
  unsigned short* woutb= (unsigned short*)p;  p += 256 * 256 * 2;
  unsigned short* wl1b = (unsigned short*)p;  p += 256 * 256 * 2;
  unsigned short* wl2b = (unsigned short*)p;  p += 256 * 256 * 2;

  k_prep<<<949, 256, 0, stream>>>(W_enc, wencb, in_proj_w, wqkb,
                                  out_proj_w, woutb, lin1_w, wl1b, lin2_w, wl2b,
                                  pe, fc1_w, fc1_b, fc2_w, fc2_b, ln2_w, ln2_b, hp);
  k_pre<<<MTOK / 64, 256, 0, stream>>>(src, wencb, b_enc, pe, wqkb, in_proj_b, xb, qkvb);
  k_attn_mfma<<<dim3((SLEN + 63) / 64, BATCH, 2), 256, 0, stream>>>(qkvb, ctxb);
  k_post<<<MTOK / 64, 256, 0, stream>>>(ctxb, woutb, out_proj_b, xb, ln1_w, ln1_b,
                                        wl1b, lin1_b, wl2b, lin2_b, hp, (float*)d_out);
}